// Round 6
// baseline (4409.193 us; speedup 1.0000x reference)
//
#include <hip/hip_runtime.h>
#include <math.h>

#define BNUM 64
#define TNUM 512
#define NJ   17
#define CC   128
#define HIDC 64

// 1/sqrt(1+1e-5)
#define RSQ 0.9999950000374997f

// bf16 <-> f32 (RNE), storage-only precision
__device__ __forceinline__ float bf2f(unsigned short u) {
    union { unsigned int i; float f; } v; v.i = ((unsigned int)u) << 16; return v.f;
}
__device__ __forceinline__ unsigned short f2bf(float f) {
    union { float f; unsigned int i; } v; v.f = f;
    return (unsigned short)((v.i + 0x7FFF + ((v.i >> 16) & 1)) >> 16);
}

// adjacency bitmasks (incl. self) and D^-1/2 per joint
constexpr unsigned ADJM[NJ] = {
    0x7u, 0xBu, 0x15u, 0xAu, 0x14u,
    0x8E0u, 0x1160u, 0x2A0u, 0x540u, 0x280u, 0x500u,
    0x3820u, 0x5840u, 0xA800u, 0x15000u, 0xA000u, 0x14000u
};
constexpr float DINV[NJ] = {
    0.5773502691896258f, 0.5773502691896258f, 0.5773502691896258f,
    0.7071067811865476f, 0.7071067811865476f,
    0.5f, 0.5f,
    0.5773502691896258f, 0.5773502691896258f,
    0.7071067811865476f, 0.7071067811865476f,
    0.5f, 0.5f,
    0.5773502691896258f, 0.5773502691896258f,
    0.7071067811865476f, 0.7071067811865476f
};

// fallback if workspace is too small even for chunk=1: write zeros (bench fails
// correctness loudly instead of crashing the container with OOB writes)
__global__ void k_fallback(float* out) { out[threadIdx.x] = 0.f; }

// ---------------- GCN core: support GEMM + adjacency mix + BN + ReLU ----------
template<int CIN>
__device__ __forceinline__ void gcn_core(const float* xs, long bt, int o,
        const float* __restrict__ gw, const float* __restrict__ gb,
        const float* __restrict__ bn1g, const float* __restrict__ bn1b,
        unsigned short* __restrict__ H1) {
    float acc[NJ];
#pragma unroll
    for (int n = 0; n < NJ; ++n) acc[n] = 0.f;

    for (int i = 0; i < CIN; i += 8) {
        float g[8];
#pragma unroll
        for (int j = 0; j < 8; ++j) g[j] = gw[(i + j) * CC + o];
#pragma unroll
        for (int n = 0; n < NJ; ++n) {
            const float4 a = *reinterpret_cast<const float4*>(&xs[n * CIN + i]);
            const float4 b = *reinterpret_cast<const float4*>(&xs[n * CIN + i + 4]);
            float t = acc[n];
            t = fmaf(a.x, g[0], t); t = fmaf(a.y, g[1], t);
            t = fmaf(a.z, g[2], t); t = fmaf(a.w, g[3], t);
            t = fmaf(b.x, g[4], t); t = fmaf(b.y, g[5], t);
            t = fmaf(b.z, g[6], t); t = fmaf(b.w, g[7], t);
            acc[n] = t;
        }
    }
    float accd[NJ];
#pragma unroll
    for (int n = 0; n < NJ; ++n) accd[n] = acc[n] * DINV[n];

    const float gbo = gb[o];
#pragma unroll
    for (int m = 0; m < NJ; ++m) {
        float ym = 0.f;
#pragma unroll
        for (int n = 0; n < NJ; ++n)
            if (ADJM[m] & (1u << n)) ym += accd[n];
        ym = fmaf(ym, DINV[m], gbo);
        const int ch = m * CC + o;
        float v = fmaf(ym, bn1g[ch] * RSQ, bn1b[ch]);
        H1[(size_t)bt * (NJ * CC) + ch] = f2bf(fmaxf(v, 0.f));
    }
}

// GCN for blocks 1,2 (Cin=128); X is bf16 (local-chunk indexed)
__global__ __launch_bounds__(128) void k_gcn(const unsigned short* __restrict__ X,
        const float* __restrict__ gw, const float* __restrict__ gb,
        const float* __restrict__ bn1g, const float* __restrict__ bn1b,
        unsigned short* __restrict__ H1) {
    __shared__ __align__(16) float xs[NJ * CC];
    const long bt = blockIdx.x;
    const int tid = threadIdx.x;
    const unsigned short* xp = X + (size_t)bt * (NJ * CC);
    for (int idx = tid; idx < NJ * CC / 4; idx += 128) {
        const ushort4 u = *reinterpret_cast<const ushort4*>(&xp[idx * 4]);
        float4 v;
        v.x = bf2f(u.x); v.y = bf2f(u.y); v.z = bf2f(u.z); v.w = bf2f(u.w);
        *reinterpret_cast<float4*>(&xs[idx * 4]) = v;
    }
    __syncthreads();
    gcn_core<CC>(xs, bt, tid, gw, gb, bn1g, bn1b, H1);
}

// GCN for block 0: fuses the 3->64 input transform; x is fp32 (chunk-offset ptr)
__global__ __launch_bounds__(128) void k_gcn0(const float* __restrict__ x,
        const float* __restrict__ w_in, const float* __restrict__ b_in,
        const float* __restrict__ gw, const float* __restrict__ gb,
        const float* __restrict__ bn1g, const float* __restrict__ bn1b,
        unsigned short* __restrict__ H1) {
    __shared__ __align__(16) float xs[NJ * HIDC];
    __shared__ float xraw[NJ * 3];
    const long bt = blockIdx.x;
    const int tid = threadIdx.x;
    if (tid < NJ * 3) xraw[tid] = x[(size_t)bt * (NJ * 3) + tid];
    __syncthreads();
    for (int idx = tid; idx < NJ * HIDC; idx += 128) {
        const int n = idx >> 6, o = idx & 63;
        xs[idx] = fmaf(xraw[n * 3 + 2], w_in[o * 3 + 2],
                  fmaf(xraw[n * 3 + 1], w_in[o * 3 + 1],
                  fmaf(xraw[n * 3 + 0], w_in[o * 3 + 0], b_in[o])));
    }
    __syncthreads();
    gcn_core<HIDC>(xs, bt, tid, gw, gb, bn1g, bn1b, H1);
}

// transpose cw [2176][128][3] -> cwT [n][i][k][o] (fp32, L2-resident at 3.3MB)
__global__ void k_cwT(const float* __restrict__ cw, float* __restrict__ cwT) {
    const int idx = blockIdx.x * 256 + threadIdx.x;
    if (idx >= NJ * CC * 3 * CC) return;
    const int o = idx & 127;
    const int r = idx >> 7;
    const int k = r % 3;
    const int i = (r / 3) % CC;
    const int n = (r / 3) / CC;
    cwT[idx] = cw[((size_t)(n * CC + o) * CC + i) * 3 + k];
}

// grouped temporal conv k=3 pad=1 + BN + ReLU + residual; H1/OUT bf16 (chunk-local)
// RES_MODE 0: identity residual (read-modify-write OUT)
// RES_MODE 1: block0 residual = BN(per-joint 64->128 proj of input-transform(x)); RSRC = raw fp32 x (chunk-offset ptr)
template<int RES_MODE>
__global__ __launch_bounds__(128) void k_tconv(
        const unsigned short* __restrict__ H1, const float* __restrict__ cwT,
        const float* __restrict__ cb,
        const float* __restrict__ bn2g, const float* __restrict__ bn2b,
        const float* __restrict__ RSRC,
        const float* __restrict__ w_in, const float* __restrict__ b_in,
        const float* __restrict__ rw, const float* __restrict__ rb,
        const float* __restrict__ rg, const float* __restrict__ rbb,
        unsigned short* __restrict__ OUT) {
    __shared__ __align__(16) float xin[34 * CC];
    __shared__ float h0s[RES_MODE ? 32 * HIDC : 1];

    const int t0 = blockIdx.x * 32;
    const int n  = blockIdx.y;
    const int b  = blockIdx.z;
    const int o  = threadIdx.x;

    for (int idx = o; idx < 34 * 32; idx += 128) {
        const int row = idx >> 5;
        const int c4  = (idx & 31) << 2;
        const int ti = t0 - 1 + row;
        float4 v = {0.f, 0.f, 0.f, 0.f};
        if (ti >= 0 && ti < TNUM) {
            const ushort4 u = *reinterpret_cast<const ushort4*>(
                &H1[(((size_t)b * TNUM + ti) * NJ + n) * CC + c4]);
            v.x = bf2f(u.x); v.y = bf2f(u.y); v.z = bf2f(u.z); v.w = bf2f(u.w);
        }
        *reinterpret_cast<float4*>(&xin[row * CC + c4]) = v;
    }
    if constexpr (RES_MODE == 1) {
        for (int idx = o; idx < 32 * HIDC; idx += 128) {
            const int t = idx >> 6, oc = idx & 63;
            const float* xb = RSRC + ((size_t)b * TNUM + t0 + t) * (NJ * 3) + n * 3;
            h0s[idx] = fmaf(xb[2], w_in[oc * 3 + 2],
                       fmaf(xb[1], w_in[oc * 3 + 1],
                       fmaf(xb[0], w_in[oc * 3 + 0], b_in[oc])));
        }
    }
    __syncthreads();

    float acc[32];
#pragma unroll
    for (int t = 0; t < 32; ++t) acc[t] = 0.f;

    const float* wp = cwT + (size_t)n * CC * 3 * CC + o;
    for (int i = 0; i < CC; i += 4) {
        float w[4][3];
#pragma unroll
        for (int j = 0; j < 4; ++j)
#pragma unroll
            for (int k = 0; k < 3; ++k) w[j][k] = wp[((i + j) * 3 + k) * CC];
#pragma unroll
        for (int r = 0; r < 34; ++r) {
            const float4 xv = *reinterpret_cast<const float4*>(&xin[r * CC + i]);
            const float vx[4] = {xv.x, xv.y, xv.z, xv.w};
#pragma unroll
            for (int j = 0; j < 4; ++j) {
                if (r < 32)            acc[r]     = fmaf(w[j][0], vx[j], acc[r]);
                if (r >= 1 && r <= 32) acc[r - 1] = fmaf(w[j][1], vx[j], acc[r - 1]);
                if (r >= 2)            acc[r - 2] = fmaf(w[j][2], vx[j], acc[r - 2]);
            }
        }
    }

    const int ch = n * CC + o;
    const float s2 = bn2g[ch] * RSQ, bb2 = bn2b[ch], cbo = cb[ch];

    if constexpr (RES_MODE == 1) {
        float racc[32];
        const float rbch = rb[ch];
#pragma unroll
        for (int t = 0; t < 32; ++t) racc[t] = rbch;
        for (int i = 0; i < HIDC; ++i) {
            const float w = rw[(size_t)ch * HIDC + i];
#pragma unroll
            for (int t = 0; t < 32; ++t)
                racc[t] = fmaf(h0s[t * HIDC + i], w, racc[t]);
        }
        const float rs = rg[ch] * RSQ, rsh = rbb[ch];
#pragma unroll
        for (int t = 0; t < 32; ++t) {
            const size_t oidx = (((size_t)b * TNUM + t0 + t) * NJ + n) * CC + o;
            const float v = fmaxf(fmaf(acc[t] + cbo, s2, bb2), 0.f);
            OUT[oidx] = f2bf(v + fmaf(racc[t], rs, rsh));
        }
    } else {
#pragma unroll
        for (int t = 0; t < 32; ++t) {
            const size_t oidx = (((size_t)b * TNUM + t0 + t) * NJ + n) * CC + o;
            const float v = fmaxf(fmaf(acc[t] + cbo, s2, bb2), 0.f);
            OUT[oidx] = f2bf(v + bf2f(OUT[oidx]));
        }
    }
}

// temporal mean pool: bf16 [chunkB,T,N,128] -> fp32 P (chunk-offset ptr) [b,N*128]
__global__ __launch_bounds__(128) void k_pool(const unsigned short* __restrict__ X,
                                              float* __restrict__ P) {
    const int b = blockIdx.x / NJ, n = blockIdx.x % NJ;
    const int o = threadIdx.x;
    const unsigned short* xp = X + ((size_t)b * TNUM * NJ + n) * CC + o;
    float s0 = 0.f, s1 = 0.f, s2 = 0.f, s3 = 0.f;
    for (int t = 0; t < TNUM; t += 4) {
        s0 += bf2f(xp[(size_t)(t + 0) * NJ * CC]);
        s1 += bf2f(xp[(size_t)(t + 1) * NJ * CC]);
        s2 += bf2f(xp[(size_t)(t + 2) * NJ * CC]);
        s3 += bf2f(xp[(size_t)(t + 3) * NJ * CC]);
    }
    P[(size_t)blockIdx.x * CC + o] = (s0 + s1 + s2 + s3) * (1.0f / TNUM);
}

// MLP head: 2176 -> 128 -> 64 -> 1, relu/relu/sigmoid
__global__ __launch_bounds__(128) void k_mlp(const float* __restrict__ P,
        const float* __restrict__ w1, const float* __restrict__ b1,
        const float* __restrict__ w2, const float* __restrict__ b2,
        const float* __restrict__ w3, const float* __restrict__ b3,
        float* __restrict__ out) {
    __shared__ float h1[128];
    __shared__ float h2[64];
    const int b = blockIdx.x, tid = threadIdx.x;
    const float* pr = P + (size_t)b * (NJ * CC);
    float acc = b1[tid];
    for (int i = 0; i < NJ * CC; ++i) acc = fmaf(pr[i], w1[i * 128 + tid], acc);
    h1[tid] = fmaxf(acc, 0.f);
    __syncthreads();
    if (tid < 64) {
        float a2 = b2[tid];
#pragma unroll 4
        for (int i = 0; i < 128; ++i) a2 = fmaf(h1[i], w2[i * 64 + tid], a2);
        h2[tid] = fmaxf(a2, 0.f);
    }
    __syncthreads();
    if (tid == 0) {
        float a3 = b3[0];
#pragma unroll 4
        for (int i = 0; i < 64; ++i) a3 = fmaf(h2[i], w3[i], a3);
        out[b] = 1.f / (1.f + expf(-a3));
    }
}

extern "C" void kernel_launch(void* const* d_in, const int* in_sizes, int n_in,
                              void* d_out, int out_size, void* d_ws, size_t ws_size,
                              hipStream_t stream) {
    const float* x    = (const float*)d_in[0];
    const float* w_in = (const float*)d_in[1];
    const float* b_in = (const float*)d_in[2];
    const float *gw[3], *gb[3], *bn1g[3], *bn1b[3], *cw[3], *cb[3], *bn2g[3], *bn2b[3];
    for (int l = 0; l < 3; ++l) {
        const int base = 3 + l * 8;
        gw[l]   = (const float*)d_in[base + 0];
        gb[l]   = (const float*)d_in[base + 1];
        bn1g[l] = (const float*)d_in[base + 2];
        bn1b[l] = (const float*)d_in[base + 3];
        cw[l]   = (const float*)d_in[base + 4];
        cb[l]   = (const float*)d_in[base + 5];
        bn2g[l] = (const float*)d_in[base + 6];
        bn2b[l] = (const float*)d_in[base + 7];
    }
    const float* rw0  = (const float*)d_in[27];
    const float* rb0  = (const float*)d_in[28];
    const float* rg0  = (const float*)d_in[29];
    const float* rbb0 = (const float*)d_in[30];
    const float* w1   = (const float*)d_in[31];
    const float* b1   = (const float*)d_in[32];
    const float* w2   = (const float*)d_in[33];
    const float* b2   = (const float*)d_in[34];
    const float* w3   = (const float*)d_in[35];
    const float* b3   = (const float*)d_in[36];

    // --- adaptive workspace plan (batch-chunked; chunk picked from ws_size) ---
    const size_t CWT    = (size_t)NJ * CC * 3 * CC;          // 835,584 fp32 elems
    const size_t ACT_B  = (size_t)TNUM * NJ * CC;            // per-batch activation elems
    const size_t POOLED = (size_t)BNUM * NJ * CC;            // fp32 elems
    const size_t fixedB = 3 * CWT * sizeof(float) + POOLED * sizeof(float); // ~10.6 MB

    int chunk = 0;
    for (int c = BNUM; c >= 1; c >>= 1) {
        const size_t need = fixedB + 2 * (size_t)c * ACT_B * sizeof(unsigned short);
        if (need <= ws_size) { chunk = c; break; }
    }
    if (chunk == 0) {  // ws too small even for chunk=1 (~15 MB): fail loudly, no OOB
        k_fallback<<<1, 64, 0, stream>>>((float*)d_out);
        return;
    }

    float* cwT0   = (float*)d_ws;
    float* cwT1   = cwT0 + CWT;
    float* cwT2   = cwT1 + CWT;
    float* pooled = cwT2 + CWT;
    unsigned short* bufA = (unsigned short*)(pooled + POOLED);
    unsigned short* bufB = bufA + (size_t)chunk * ACT_B;

    // weight transposes (once per call)
    k_cwT<<<(int)((CWT + 255) / 256), 256, 0, stream>>>(cw[0], cwT0);
    k_cwT<<<(int)((CWT + 255) / 256), 256, 0, stream>>>(cw[1], cwT1);
    k_cwT<<<(int)((CWT + 255) / 256), 256, 0, stream>>>(cw[2], cwT2);

    for (int b0 = 0; b0 < BNUM; b0 += chunk) {
        const float* xc = x + (size_t)b0 * TNUM * NJ * 3;
        const int BT = chunk * TNUM;
        const dim3 tgrid(TNUM / 32, NJ, chunk);

        // block 0 (fused input transform; conv residual from raw x)
        k_gcn0<<<BT, 128, 0, stream>>>(xc, w_in, b_in, gw[0], gb[0], bn1g[0], bn1b[0], bufA);
        k_tconv<1><<<tgrid, 128, 0, stream>>>(bufA, cwT0, cb[0], bn2g[0], bn2b[0],
                                              xc, w_in, b_in, rw0, rb0, rg0, rbb0, bufB);
        // block 1 (identity residual, read-modify-write on bufB)
        k_gcn<<<BT, 128, 0, stream>>>(bufB, gw[1], gb[1], bn1g[1], bn1b[1], bufA);
        k_tconv<0><<<tgrid, 128, 0, stream>>>(bufA, cwT1, cb[1], bn2g[1], bn2b[1],
                                              nullptr, w_in, b_in, nullptr, nullptr, nullptr, nullptr, bufB);
        // block 2
        k_gcn<<<BT, 128, 0, stream>>>(bufB, gw[2], gb[2], bn1g[2], bn1b[2], bufA);
        k_tconv<0><<<tgrid, 128, 0, stream>>>(bufA, cwT2, cb[2], bn2g[2], bn2b[2],
                                              nullptr, w_in, b_in, nullptr, nullptr, nullptr, nullptr, bufB);

        k_pool<<<chunk * NJ, 128, 0, stream>>>(bufB, pooled + (size_t)b0 * NJ * CC);
    }

    k_mlp<<<BNUM, 128, 0, stream>>>(pooled, w1, b1, w2, b2, w3, b3, (float*)d_out);
}

// Round 7
// 1578.138 us; speedup vs baseline: 2.7939x; 2.7939x over previous
//
#include <hip/hip_runtime.h>
#include <math.h>

#define BNUM 64
#define TNUM 512
#define NJ   17
#define CC   128
#define HIDC 64

// 1/sqrt(1+1e-5)
#define RSQ 0.9999950000374997f

typedef __attribute__((ext_vector_type(8))) short bf16x8;
typedef __attribute__((ext_vector_type(4))) float f32x4;

// bf16 <-> f32 (RNE), storage-only precision
__device__ __forceinline__ float bf2f(unsigned short u) {
    union { unsigned int i; float f; } v; v.i = ((unsigned int)u) << 16; return v.f;
}
__device__ __forceinline__ unsigned short f2bf(float f) {
    union { float f; unsigned int i; } v; v.f = f;
    return (unsigned short)((v.i + 0x7FFF + ((v.i >> 16) & 1)) >> 16);
}

// adjacency bitmasks (incl. self) and D^-1/2 per joint
constexpr unsigned ADJM[NJ] = {
    0x7u, 0xBu, 0x15u, 0xAu, 0x14u,
    0x8E0u, 0x1160u, 0x2A0u, 0x540u, 0x280u, 0x500u,
    0x3820u, 0x5840u, 0xA800u, 0x15000u, 0xA000u, 0x14000u
};
constexpr float DINV[NJ] = {
    0.5773502691896258f, 0.5773502691896258f, 0.5773502691896258f,
    0.7071067811865476f, 0.7071067811865476f,
    0.5f, 0.5f,
    0.5773502691896258f, 0.5773502691896258f,
    0.7071067811865476f, 0.7071067811865476f,
    0.5f, 0.5f,
    0.5773502691896258f, 0.5773502691896258f,
    0.7071067811865476f, 0.7071067811865476f
};

__global__ void k_fallback(float* out) { out[threadIdx.x] = 0.f; }

// ---------------- GCN core: support GEMM + adjacency mix + BN + ReLU ----------
template<int CIN>
__device__ __forceinline__ void gcn_core(const float* xs, long bt, int o,
        const float* __restrict__ gw, const float* __restrict__ gb,
        const float* __restrict__ bn1g, const float* __restrict__ bn1b,
        unsigned short* __restrict__ H1) {
    float acc[NJ];
#pragma unroll
    for (int n = 0; n < NJ; ++n) acc[n] = 0.f;

    for (int i = 0; i < CIN; i += 8) {
        float g[8];
#pragma unroll
        for (int j = 0; j < 8; ++j) g[j] = gw[(i + j) * CC + o];
#pragma unroll
        for (int n = 0; n < NJ; ++n) {
            const float4 a = *reinterpret_cast<const float4*>(&xs[n * CIN + i]);
            const float4 b = *reinterpret_cast<const float4*>(&xs[n * CIN + i + 4]);
            float t = acc[n];
            t = fmaf(a.x, g[0], t); t = fmaf(a.y, g[1], t);
            t = fmaf(a.z, g[2], t); t = fmaf(a.w, g[3], t);
            t = fmaf(b.x, g[4], t); t = fmaf(b.y, g[5], t);
            t = fmaf(b.z, g[6], t); t = fmaf(b.w, g[7], t);
            acc[n] = t;
        }
    }
    float accd[NJ];
#pragma unroll
    for (int n = 0; n < NJ; ++n) accd[n] = acc[n] * DINV[n];

    const float gbo = gb[o];
#pragma unroll
    for (int m = 0; m < NJ; ++m) {
        float ym = 0.f;
#pragma unroll
        for (int n = 0; n < NJ; ++n)
            if (ADJM[m] & (1u << n)) ym += accd[n];
        ym = fmaf(ym, DINV[m], gbo);
        const int ch = m * CC + o;
        float v = fmaf(ym, bn1g[ch] * RSQ, bn1b[ch]);
        H1[(size_t)bt * (NJ * CC) + ch] = f2bf(fmaxf(v, 0.f));
    }
}

// GCN for blocks 1,2 (Cin=128); X is bf16 (chunk-local)
__global__ __launch_bounds__(128) void k_gcn(const unsigned short* __restrict__ X,
        const float* __restrict__ gw, const float* __restrict__ gb,
        const float* __restrict__ bn1g, const float* __restrict__ bn1b,
        unsigned short* __restrict__ H1) {
    __shared__ __align__(16) float xs[NJ * CC];
    const long bt = blockIdx.x;
    const int tid = threadIdx.x;
    const unsigned short* xp = X + (size_t)bt * (NJ * CC);
    for (int idx = tid; idx < NJ * CC / 4; idx += 128) {
        const ushort4 u = *reinterpret_cast<const ushort4*>(&xp[idx * 4]);
        float4 v;
        v.x = bf2f(u.x); v.y = bf2f(u.y); v.z = bf2f(u.z); v.w = bf2f(u.w);
        *reinterpret_cast<float4*>(&xs[idx * 4]) = v;
    }
    __syncthreads();
    gcn_core<CC>(xs, bt, tid, gw, gb, bn1g, bn1b, H1);
}

// GCN for block 0: fuses the 3->64 input transform; x fp32 (chunk-offset ptr)
__global__ __launch_bounds__(128) void k_gcn0(const float* __restrict__ x,
        const float* __restrict__ w_in, const float* __restrict__ b_in,
        const float* __restrict__ gw, const float* __restrict__ gb,
        const float* __restrict__ bn1g, const float* __restrict__ bn1b,
        unsigned short* __restrict__ H1) {
    __shared__ __align__(16) float xs[NJ * HIDC];
    __shared__ float xraw[NJ * 3];
    const long bt = blockIdx.x;
    const int tid = threadIdx.x;
    if (tid < NJ * 3) xraw[tid] = x[(size_t)bt * (NJ * 3) + tid];
    __syncthreads();
    for (int idx = tid; idx < NJ * HIDC; idx += 128) {
        const int n = idx >> 6, o = idx & 63;
        xs[idx] = fmaf(xraw[n * 3 + 2], w_in[o * 3 + 2],
                  fmaf(xraw[n * 3 + 1], w_in[o * 3 + 1],
                  fmaf(xraw[n * 3 + 0], w_in[o * 3 + 0], b_in[o])));
    }
    __syncthreads();
    gcn_core<HIDC>(xs, bt, tid, gw, gb, bn1g, bn1b, H1);
}

// pack conv weights: cw [2176][128][3] fp32 -> cwB [oc][k*128+i] bf16
__global__ void k_prep_cwB(const float* __restrict__ cw, unsigned short* __restrict__ cwB) {
    const int idx = blockIdx.x * 256 + threadIdx.x;
    if (idx >= NJ * CC * 3 * CC) return;
    const int oc = idx / 384, kk = idx % 384;
    const int ktap = kk >> 7, i = kk & 127;
    cwB[idx] = f2bf(cw[((size_t)oc * CC + i) * 3 + ktap]);
}
// pack residual weights: rw [2176][64][1] fp32 -> bf16 (same layout)
__global__ void k_prep_rwB(const float* __restrict__ rw, unsigned short* __restrict__ rwB) {
    const int idx = blockIdx.x * 256 + threadIdx.x;
    if (idx >= NJ * CC * HIDC) return;
    rwB[idx] = f2bf(rw[idx]);
}

// ---------------- MFMA grouped temporal conv (k=3, pad=1) + BN + ReLU + residual
// Per block: one joint n, 64 time rows, all 128 out channels. 4 waves; wave w
// owns out-channel range [w*32, w*32+32). A (im2col of H1) staged in LDS with
// XOR swizzle (row-stride 256B would be 16-way bank conflict otherwise).
// RES_MODE 0: identity residual (RMW on OUT). RES_MODE 1: residual GEMM vs rwB
// on h0 = input-transform(x), 2 extra K-steps into a second accumulator.
template<int RES_MODE>
__global__ __launch_bounds__(256) void k_tconv_mfma(
        const unsigned short* __restrict__ H1, const unsigned short* __restrict__ cwB,
        const float* __restrict__ cb,
        const float* __restrict__ bn2g, const float* __restrict__ bn2b,
        const float* __restrict__ RSRC,
        const float* __restrict__ w_in, const float* __restrict__ b_in,
        const unsigned short* __restrict__ rwB, const float* __restrict__ rb,
        const float* __restrict__ rg, const float* __restrict__ rbb,
        unsigned short* __restrict__ OUT) {
    __shared__ __align__(16) unsigned short xin[66 * 128];
    __shared__ __align__(16) unsigned short h0s[RES_MODE ? 64 * 64 : 8];

    const int t0  = blockIdx.x * 64;
    const int n   = blockIdx.y;
    const int b   = blockIdx.z;
    const int tid = threadIdx.x;
    const int lane = tid & 63;
    const int wnt  = tid >> 6;          // wave id -> out-channel quarter

    // stage xin rows t0-1 .. t0+64 (66 x 128 bf16), 16B chunks, XOR-swizzled
    for (int c = tid; c < 66 * 16; c += 256) {
        const int row = c >> 4, slot = c & 15;
        const int ti = t0 - 1 + row;
        uint4 v = {0u, 0u, 0u, 0u};
        if (ti >= 0 && ti < TNUM)
            v = *reinterpret_cast<const uint4*>(
                    &H1[(((size_t)b * TNUM + ti) * NJ + n) * CC + slot * 8]);
        const int u = (row * 128 + slot * 8) ^ ((row & 7) << 3);
        *reinterpret_cast<uint4*>(&xin[u]) = v;
    }
    if constexpr (RES_MODE == 1) {
        for (int c = tid; c < 64 * 8; c += 256) {
            const int r = c >> 3, i8 = c & 7;
            const float* xb = &RSRC[((size_t)b * TNUM + t0 + r) * (NJ * 3) + n * 3];
            const float x0 = xb[0], x1 = xb[1], x2 = xb[2];
            unsigned short tmp[8];
#pragma unroll
            for (int j = 0; j < 8; ++j) {
                const int i = i8 * 8 + j;
                tmp[j] = f2bf(fmaf(x2, w_in[i * 3 + 2],
                              fmaf(x1, w_in[i * 3 + 1],
                              fmaf(x0, w_in[i * 3 + 0], b_in[i]))));
            }
            const int u = (r * 64 + i8 * 8) ^ ((r & 7) << 3);
            *reinterpret_cast<uint4*>(&h0s[u]) = *reinterpret_cast<uint4*>(tmp);
        }
    }
    __syncthreads();

    const int rbase = lane & 15;        // A row / B col / D col within 16-tile
    const int g8    = (lane >> 4) * 8;  // k-slot base within 32-K step

    f32x4 acc[4][2] = {};
    for (int ks = 0; ks < 12; ++ks) {
        const int ktap = ks >> 2;
        const int ib   = (ks & 3) * 32 + g8;
        bf16x8 a[4];
#pragma unroll
        for (int m = 0; m < 4; ++m) {
            const int rl = m * 16 + rbase + ktap;   // im2col: time shift by tap
            a[m] = *reinterpret_cast<const bf16x8*>(
                       &xin[(rl * 128 + ib) ^ ((rl & 7) << 3)]);
        }
#pragma unroll
        for (int nt = 0; nt < 2; ++nt) {
            const int o = wnt * 32 + nt * 16 + rbase;
            const bf16x8 bf = *reinterpret_cast<const bf16x8*>(
                &cwB[(size_t)(n * CC + o) * 384 + ks * 32 + g8]);
#pragma unroll
            for (int m = 0; m < 4; ++m)
                acc[m][nt] = __builtin_amdgcn_mfma_f32_16x16x32_bf16(a[m], bf, acc[m][nt], 0, 0, 0);
        }
    }

    f32x4 accr[4][2] = {};
    if constexpr (RES_MODE == 1) {
        for (int ks = 0; ks < 2; ++ks) {
            const int ib = ks * 32 + g8;
            bf16x8 a[4];
#pragma unroll
            for (int m = 0; m < 4; ++m) {
                const int rl = m * 16 + rbase;
                a[m] = *reinterpret_cast<const bf16x8*>(
                           &h0s[(rl * 64 + ib) ^ ((rl & 7) << 3)]);
            }
#pragma unroll
            for (int nt = 0; nt < 2; ++nt) {
                const int o = wnt * 32 + nt * 16 + rbase;
                const bf16x8 bf = *reinterpret_cast<const bf16x8*>(
                    &rwB[(size_t)(n * CC + o) * HIDC + ib]);
#pragma unroll
                for (int m = 0; m < 4; ++m)
                    accr[m][nt] = __builtin_amdgcn_mfma_f32_16x16x32_bf16(a[m], bf, accr[m][nt], 0, 0, 0);
            }
        }
    }

    // epilogue: BN + ReLU + residual, bf16 store
    const int rrow = (lane >> 4) * 4;
#pragma unroll
    for (int nt = 0; nt < 2; ++nt) {
        const int o  = wnt * 32 + nt * 16 + rbase;
        const int ch = n * CC + o;
        const float s2 = bn2g[ch] * RSQ, bb2 = bn2b[ch], cbo = cb[ch];
        float rs = 0.f, rsh = 0.f, rbc = 0.f;
        if constexpr (RES_MODE == 1) { rs = rg[ch] * RSQ; rsh = rbb[ch]; rbc = rb[ch]; }
#pragma unroll
        for (int m = 0; m < 4; ++m) {
#pragma unroll
            for (int q = 0; q < 4; ++q) {
                const int r = m * 16 + rrow + q;
                const size_t oi = (((size_t)b * TNUM + t0 + r) * NJ + n) * CC + o;
                float v = fmaxf(fmaf(acc[m][nt][q] + cbo, s2, bb2), 0.f);
                if constexpr (RES_MODE == 1) v += fmaf(accr[m][nt][q] + rbc, rs, rsh);
                else                         v += bf2f(OUT[oi]);
                OUT[oi] = f2bf(v);
            }
        }
    }
}

// temporal mean pool: bf16 [chunkB,T,N,128] -> fp32 P (chunk-offset ptr)
__global__ __launch_bounds__(128) void k_pool(const unsigned short* __restrict__ X,
                                              float* __restrict__ P) {
    const int b = blockIdx.x / NJ, n = blockIdx.x % NJ;
    const int o = threadIdx.x;
    const unsigned short* xp = X + ((size_t)b * TNUM * NJ + n) * CC + o;
    float s0 = 0.f, s1 = 0.f, s2 = 0.f, s3 = 0.f;
    for (int t = 0; t < TNUM; t += 4) {
        s0 += bf2f(xp[(size_t)(t + 0) * NJ * CC]);
        s1 += bf2f(xp[(size_t)(t + 1) * NJ * CC]);
        s2 += bf2f(xp[(size_t)(t + 2) * NJ * CC]);
        s3 += bf2f(xp[(size_t)(t + 3) * NJ * CC]);
    }
    P[(size_t)blockIdx.x * CC + o] = (s0 + s1 + s2 + s3) * (1.0f / TNUM);
}

// MLP head: 2176 -> 128 -> 64 -> 1, relu/relu/sigmoid
__global__ __launch_bounds__(128) void k_mlp(const float* __restrict__ P,
        const float* __restrict__ w1, const float* __restrict__ b1,
        const float* __restrict__ w2, const float* __restrict__ b2,
        const float* __restrict__ w3, const float* __restrict__ b3,
        float* __restrict__ out) {
    __shared__ float h1[128];
    __shared__ float h2[64];
    const int b = blockIdx.x, tid = threadIdx.x;
    const float* pr = P + (size_t)b * (NJ * CC);
    float acc = b1[tid];
    for (int i = 0; i < NJ * CC; ++i) acc = fmaf(pr[i], w1[i * 128 + tid], acc);
    h1[tid] = fmaxf(acc, 0.f);
    __syncthreads();
    if (tid < 64) {
        float a2 = b2[tid];
#pragma unroll 4
        for (int i = 0; i < 128; ++i) a2 = fmaf(h1[i], w2[i * 64 + tid], a2);
        h2[tid] = fmaxf(a2, 0.f);
    }
    __syncthreads();
    if (tid == 0) {
        float a3 = b3[0];
#pragma unroll 4
        for (int i = 0; i < 64; ++i) a3 = fmaf(h2[i], w3[i], a3);
        out[b] = 1.f / (1.f + expf(-a3));
    }
}

extern "C" void kernel_launch(void* const* d_in, const int* in_sizes, int n_in,
                              void* d_out, int out_size, void* d_ws, size_t ws_size,
                              hipStream_t stream) {
    const float* x    = (const float*)d_in[0];
    const float* w_in = (const float*)d_in[1];
    const float* b_in = (const float*)d_in[2];
    const float *gw[3], *gb[3], *bn1g[3], *bn1b[3], *cw[3], *cb[3], *bn2g[3], *bn2b[3];
    for (int l = 0; l < 3; ++l) {
        const int base = 3 + l * 8;
        gw[l]   = (const float*)d_in[base + 0];
        gb[l]   = (const float*)d_in[base + 1];
        bn1g[l] = (const float*)d_in[base + 2];
        bn1b[l] = (const float*)d_in[base + 3];
        cw[l]   = (const float*)d_in[base + 4];
        cb[l]   = (const float*)d_in[base + 5];
        bn2g[l] = (const float*)d_in[base + 6];
        bn2b[l] = (const float*)d_in[base + 7];
    }
    const float* rw0  = (const float*)d_in[27];
    const float* rb0  = (const float*)d_in[28];
    const float* rg0  = (const float*)d_in[29];
    const float* rbb0 = (const float*)d_in[30];
    const float* w1   = (const float*)d_in[31];
    const float* b1   = (const float*)d_in[32];
    const float* w2   = (const float*)d_in[33];
    const float* b2   = (const float*)d_in[34];
    const float* w3   = (const float*)d_in[35];
    const float* b3   = (const float*)d_in[36];

    // --- adaptive workspace plan (batch-chunked; chunk picked from ws_size) ---
    const size_t CWB    = (size_t)NJ * CC * 3 * CC;   // 835,584 bf16 elems per layer
    const size_t RWB    = (size_t)NJ * CC * HIDC;     // 139,264 bf16 elems
    const size_t ACT_B  = (size_t)TNUM * NJ * CC;     // per-batch activation elems
    const size_t POOLED = (size_t)BNUM * NJ * CC;     // fp32 elems
    const size_t fixedB = (3 * CWB + RWB) * sizeof(unsigned short)
                        + POOLED * sizeof(float);     // ~5.85 MB

    int chunk = 0;
    for (int c = BNUM; c >= 1; c >>= 1) {
        const size_t need = fixedB + 2 * (size_t)c * ACT_B * sizeof(unsigned short);
        if (need <= ws_size) { chunk = c; break; }
    }
    if (chunk == 0) {
        k_fallback<<<1, 64, 0, stream>>>((float*)d_out);
        return;
    }

    unsigned short* cwB0 = (unsigned short*)d_ws;
    unsigned short* cwB1 = cwB0 + CWB;
    unsigned short* cwB2 = cwB1 + CWB;
    unsigned short* rwB  = cwB2 + CWB;
    float* pooled = (float*)(rwB + RWB);
    unsigned short* bufA = (unsigned short*)(pooled + POOLED);
    unsigned short* bufB = bufA + (size_t)chunk * ACT_B;

    // weight packs (once per call)
    k_prep_cwB<<<(int)((CWB + 255) / 256), 256, 0, stream>>>(cw[0], cwB0);
    k_prep_cwB<<<(int)((CWB + 255) / 256), 256, 0, stream>>>(cw[1], cwB1);
    k_prep_cwB<<<(int)((CWB + 255) / 256), 256, 0, stream>>>(cw[2], cwB2);
    k_prep_rwB<<<(int)((RWB + 255) / 256), 256, 0, stream>>>(rw0, rwB);

    for (int b0 = 0; b0 < BNUM; b0 += chunk) {
        const float* xc = x + (size_t)b0 * TNUM * NJ * 3;
        const int BT = chunk * TNUM;
        const dim3 tgrid(TNUM / 64, NJ, chunk);

        // block 0 (fused input transform; conv-path residual via rwB K-steps)
        k_gcn0<<<BT, 128, 0, stream>>>(xc, w_in, b_in, gw[0], gb[0], bn1g[0], bn1b[0], bufA);
        k_tconv_mfma<1><<<tgrid, 256, 0, stream>>>(bufA, cwB0, cb[0], bn2g[0], bn2b[0],
                                                   xc, w_in, b_in, rwB, rb0, rg0, rbb0, bufB);
        // block 1 (identity residual, RMW on bufB)
        k_gcn<<<BT, 128, 0, stream>>>(bufB, gw[1], gb[1], bn1g[1], bn1b[1], bufA);
        k_tconv_mfma<0><<<tgrid, 256, 0, stream>>>(bufA, cwB1, cb[1], bn2g[1], bn2b[1],
                                                   nullptr, w_in, b_in, nullptr, nullptr, nullptr, nullptr, bufB);
        // block 2
        k_gcn<<<BT, 128, 0, stream>>>(bufB, gw[2], gb[2], bn1g[2], bn1b[2], bufA);
        k_tconv_mfma<0><<<tgrid, 256, 0, stream>>>(bufA, cwB2, cb[2], bn2g[2], bn2b[2],
                                                   nullptr, w_in, b_in, nullptr, nullptr, nullptr, nullptr, bufB);

        k_pool<<<chunk * NJ, 128, 0, stream>>>(bufB, pooled + (size_t)b0 * NJ * CC);
    }

    k_mlp<<<BNUM, 128, 0, stream>>>(pooled, w1, b1, w2, b2, w3, b3, (float*)d_out);
}

// Round 8
// 1069.496 us; speedup vs baseline: 4.1227x; 1.4756x over previous
//
#include <hip/hip_runtime.h>
#include <math.h>

#define BNUM 64
#define TNUM 512
#define NJ   17
#define CC   128
#define HIDC 64

// 1/sqrt(1+1e-5)
#define RSQ 0.9999950000374997f

typedef __attribute__((ext_vector_type(8))) short bf16x8;
typedef __attribute__((ext_vector_type(4))) float f32x4;

__device__ __forceinline__ float bf2f(unsigned short u) {
    union { unsigned int i; float f; } v; v.i = ((unsigned int)u) << 16; return v.f;
}
__device__ __forceinline__ unsigned short f2bf(float f) {
    union { float f; unsigned int i; } v; v.f = f;
    return (unsigned short)((v.i + 0x7FFF + ((v.i >> 16) & 1)) >> 16);
}

constexpr unsigned ADJM[NJ] = {
    0x7u, 0xBu, 0x15u, 0xAu, 0x14u,
    0x8E0u, 0x1160u, 0x2A0u, 0x540u, 0x280u, 0x500u,
    0x3820u, 0x5840u, 0xA800u, 0x15000u, 0xA000u, 0x14000u
};
constexpr float DINV[NJ] = {
    0.5773502691896258f, 0.5773502691896258f, 0.5773502691896258f,
    0.7071067811865476f, 0.7071067811865476f,
    0.5f, 0.5f,
    0.5773502691896258f, 0.5773502691896258f,
    0.7071067811865476f, 0.7071067811865476f,
    0.5f, 0.5f,
    0.5773502691896258f, 0.5773502691896258f,
    0.7071067811865476f, 0.7071067811865476f
};

__global__ void k_fallback(float* out) { out[threadIdx.x] = 0.f; }

// pack conv weights: cw [2176][128][3] fp32 -> cwB [oc][k*128+i] bf16
__global__ void k_prep_cwB(const float* __restrict__ cw, unsigned short* __restrict__ cwB) {
    const int idx = blockIdx.x * 256 + threadIdx.x;
    if (idx >= NJ * CC * 3 * CC) return;
    const int oc = idx / 384, kk = idx % 384;
    const int ktap = kk >> 7, i = kk & 127;
    cwB[idx] = f2bf(cw[((size_t)oc * CC + i) * 3 + ktap]);
}
// pack residual weights: rw [2176][64] fp32 -> bf16
__global__ void k_prep_rwB(const float* __restrict__ rw, unsigned short* __restrict__ rwB) {
    const int idx = blockIdx.x * 256 + threadIdx.x;
    if (idx >= NJ * CC * HIDC) return;
    rwB[idx] = f2bf(rw[idx]);
}
// pack gcn weights: gw [CIN][128] fp32 -> gwB [o][i] bf16 (transposed)
template<int CIN>
__global__ void k_prep_gwB(const float* __restrict__ gw, unsigned short* __restrict__ gwB) {
    const int idx = blockIdx.x * 256 + threadIdx.x;
    if (idx >= CC * CIN) return;
    const int o = idx / CIN, i = idx % CIN;
    gwB[idx] = f2bf(gw[i * CC + o]);
}

// ---------------- fused MFMA GCN: support GEMM + adjacency mix + BN + ReLU ----
// Block = 16 bt rows x 17 joints = 272 GEMM rows (17 M-tiles), 4 waves.
// Wave w computes out-channels [w*32, w*32+32) for all 17 M-tiles.
// Phase 1: stage A (272 x CIN bf16) in LDS, XOR-swizzled.
// Phase 2: MFMA K-loop, acc[17][2] f32x4.
// Phase 3: S back into same LDS (barrier-separated).
// Phase 4: adjacency mix + BN + ReLU from LDS -> H1 global (coalesced).
template<int CIN>
__device__ __forceinline__ void gcn_mfma_body(
        const unsigned short* __restrict__ gwB,
        const float* __restrict__ gb,
        const float* __restrict__ bn1g, const float* __restrict__ bn1b,
        unsigned short* __restrict__ H1, unsigned short* lds,
        int bt0, int tid) {
    const int lane = tid & 63;
    const int wnt  = tid >> 6;
    const int rbase = lane & 15;
    const int g8    = (lane >> 4) * 8;

    f32x4 acc[17][2] = {};
#pragma unroll
    for (int ks = 0; ks < CIN / 32; ++ks) {
        bf16x8 bfr[2];
#pragma unroll
        for (int nt = 0; nt < 2; ++nt)
            bfr[nt] = *reinterpret_cast<const bf16x8*>(
                &gwB[(size_t)(wnt * 32 + nt * 16 + rbase) * CIN + ks * 32 + g8]);
#pragma unroll
        for (int mt = 0; mt < 17; ++mt) {
            const int rl = mt * 16 + rbase;
            const bf16x8 a = *reinterpret_cast<const bf16x8*>(
                &lds[(rl * CIN + ks * 32 + g8) ^ ((rl & 7) << 3)]);
            acc[mt][0] = __builtin_amdgcn_mfma_f32_16x16x32_bf16(a, bfr[0], acc[mt][0], 0, 0, 0);
            acc[mt][1] = __builtin_amdgcn_mfma_f32_16x16x32_bf16(a, bfr[1], acc[mt][1], 0, 0, 0);
        }
    }
    __syncthreads();

    // S -> LDS [272][128], swizzled
    const int rrow = (lane >> 4) * 4;
#pragma unroll
    for (int mt = 0; mt < 17; ++mt)
#pragma unroll
        for (int nt = 0; nt < 2; ++nt)
#pragma unroll
            for (int q = 0; q < 4; ++q) {
                const int r = mt * 16 + rrow + q;
                const int o = wnt * 32 + nt * 16 + rbase;
                lds[(r * 128 + o) ^ ((r & 7) << 3)] = f2bf(acc[mt][nt][q]);
            }
    __syncthreads();

    // adjacency mix + BN + ReLU
    const int o    = tid & 127;
    const int half = tid >> 7;          // 0..1 -> 8 bts each
    float gbo[NJ], s1c[NJ], b1c[NJ];
#pragma unroll
    for (int m = 0; m < NJ; ++m) {
        const int ch = m * CC + o;
        gbo[m] = gb[ch];
        s1c[m] = bn1g[ch] * RSQ;
        b1c[m] = bn1b[ch];
    }
    for (int j = 0; j < 8; ++j) {
        const int btl = half * 8 + j;
        float s[NJ];
#pragma unroll
        for (int n = 0; n < NJ; ++n) {
            const int r = btl * NJ + n;
            s[n] = bf2f(lds[(r * 128 + o) ^ ((r & 7) << 3)]) * DINV[n];
        }
        unsigned short outv[NJ];
#pragma unroll
        for (int m = 0; m < NJ; ++m) {
            float ym = 0.f;
#pragma unroll
            for (int n = 0; n < NJ; ++n)
                if (ADJM[m] & (1u << n)) ym += s[n];
            ym = fmaf(ym, DINV[m], gbo[m]);
            outv[m] = f2bf(fmaxf(fmaf(ym, s1c[m], b1c[m]), 0.f));
        }
        unsigned short* hp = &H1[(size_t)(bt0 + btl) * (NJ * CC) + o];
#pragma unroll
        for (int m = 0; m < NJ; ++m) hp[m * CC] = outv[m];
    }
}

// layers 1,2: A = X (bf16 [bt][17][128])
__global__ __launch_bounds__(256, 1) void k_gcn_mfma(
        const unsigned short* __restrict__ X, const unsigned short* __restrict__ gwB,
        const float* __restrict__ gb,
        const float* __restrict__ bn1g, const float* __restrict__ bn1b,
        unsigned short* __restrict__ H1) {
    __shared__ __align__(16) unsigned short lds[272 * 128];
    const int bt0 = blockIdx.x * 16;
    const int tid = threadIdx.x;
    for (int c = tid; c < 272 * 16; c += 256) {
        const int rl = c >> 4, s8 = c & 15;
        const uint4 v = *reinterpret_cast<const uint4*>(
            &X[(size_t)(bt0 * NJ + rl) * CC + s8 * 8]);
        *reinterpret_cast<uint4*>(&lds[(rl * 128 + s8 * 8) ^ ((rl & 7) << 3)]) = v;
    }
    __syncthreads();
    gcn_mfma_body<CC>(gwB, gb, bn1g, bn1b, H1, lds, bt0, tid);
}

// layer 0: A computed on the fly from raw x via the 3->64 input transform
__global__ __launch_bounds__(256, 1) void k_gcn0_mfma(
        const float* __restrict__ x,
        const float* __restrict__ w_in, const float* __restrict__ b_in,
        const unsigned short* __restrict__ gwB,
        const float* __restrict__ gb,
        const float* __restrict__ bn1g, const float* __restrict__ bn1b,
        unsigned short* __restrict__ H1) {
    __shared__ __align__(16) unsigned short lds[272 * 128];
    const int bt0 = blockIdx.x * 16;
    const int tid = threadIdx.x;
    for (int c = tid; c < 272 * 8; c += 256) {
        const int rl = c >> 3, i8 = c & 7;
        const int bt = bt0 + rl / NJ, n = rl % NJ;
        const float* xb = &x[(size_t)bt * (NJ * 3) + n * 3];
        const float x0 = xb[0], x1 = xb[1], x2 = xb[2];
        unsigned short tmp[8];
#pragma unroll
        for (int jj = 0; jj < 8; ++jj) {
            const int i = i8 * 8 + jj;
            tmp[jj] = f2bf(fmaf(x2, w_in[i * 3 + 2],
                           fmaf(x1, w_in[i * 3 + 1],
                           fmaf(x0, w_in[i * 3 + 0], b_in[i]))));
        }
        *reinterpret_cast<uint4*>(&lds[(rl * HIDC + i8 * 8) ^ ((rl & 7) << 3)]) =
            *reinterpret_cast<uint4*>(tmp);
    }
    __syncthreads();
    gcn_mfma_body<HIDC>(gwB, gb, bn1g, bn1b, H1, lds, bt0, tid);
}

// ---------------- MFMA grouped temporal conv (k=3, pad=1) + BN + ReLU + residual
template<int RES_MODE>
__global__ __launch_bounds__(256) void k_tconv_mfma(
        const unsigned short* __restrict__ H1, const unsigned short* __restrict__ cwB,
        const float* __restrict__ cb,
        const float* __restrict__ bn2g, const float* __restrict__ bn2b,
        const float* __restrict__ RSRC,
        const float* __restrict__ w_in, const float* __restrict__ b_in,
        const unsigned short* __restrict__ rwB, const float* __restrict__ rb,
        const float* __restrict__ rg, const float* __restrict__ rbb,
        unsigned short* __restrict__ OUT) {
    __shared__ __align__(16) unsigned short xin[66 * 128];
    __shared__ __align__(16) unsigned short h0s[RES_MODE ? 64 * 64 : 8];

    const int t0  = blockIdx.x * 64;
    const int n   = blockIdx.y;
    const int b   = blockIdx.z;
    const int tid = threadIdx.x;
    const int lane = tid & 63;
    const int wnt  = tid >> 6;

    for (int c = tid; c < 66 * 16; c += 256) {
        const int row = c >> 4, slot = c & 15;
        const int ti = t0 - 1 + row;
        uint4 v = {0u, 0u, 0u, 0u};
        if (ti >= 0 && ti < TNUM)
            v = *reinterpret_cast<const uint4*>(
                    &H1[(((size_t)b * TNUM + ti) * NJ + n) * CC + slot * 8]);
        const int u = (row * 128 + slot * 8) ^ ((row & 7) << 3);
        *reinterpret_cast<uint4*>(&xin[u]) = v;
    }
    if constexpr (RES_MODE == 1) {
        for (int c = tid; c < 64 * 8; c += 256) {
            const int r = c >> 3, i8 = c & 7;
            const float* xb = &RSRC[((size_t)b * TNUM + t0 + r) * (NJ * 3) + n * 3];
            const float x0 = xb[0], x1 = xb[1], x2 = xb[2];
            unsigned short tmp[8];
#pragma unroll
            for (int j = 0; j < 8; ++j) {
                const int i = i8 * 8 + j;
                tmp[j] = f2bf(fmaf(x2, w_in[i * 3 + 2],
                              fmaf(x1, w_in[i * 3 + 1],
                              fmaf(x0, w_in[i * 3 + 0], b_in[i]))));
            }
            const int u = (r * 64 + i8 * 8) ^ ((r & 7) << 3);
            *reinterpret_cast<uint4*>(&h0s[u]) = *reinterpret_cast<uint4*>(tmp);
        }
    }
    __syncthreads();

    const int rbase = lane & 15;
    const int g8    = (lane >> 4) * 8;

    f32x4 acc[4][2] = {};
    for (int ks = 0; ks < 12; ++ks) {
        const int ktap = ks >> 2;
        const int ib   = (ks & 3) * 32 + g8;
        bf16x8 a[4];
#pragma unroll
        for (int m = 0; m < 4; ++m) {
            const int rl = m * 16 + rbase + ktap;
            a[m] = *reinterpret_cast<const bf16x8*>(
                       &xin[(rl * 128 + ib) ^ ((rl & 7) << 3)]);
        }
#pragma unroll
        for (int nt = 0; nt < 2; ++nt) {
            const int o = wnt * 32 + nt * 16 + rbase;
            const bf16x8 bf = *reinterpret_cast<const bf16x8*>(
                &cwB[(size_t)(n * CC + o) * 384 + ks * 32 + g8]);
#pragma unroll
            for (int m = 0; m < 4; ++m)
                acc[m][nt] = __builtin_amdgcn_mfma_f32_16x16x32_bf16(a[m], bf, acc[m][nt], 0, 0, 0);
        }
    }

    f32x4 accr[4][2] = {};
    if constexpr (RES_MODE == 1) {
        for (int ks = 0; ks < 2; ++ks) {
            const int ib = ks * 32 + g8;
            bf16x8 a[4];
#pragma unroll
            for (int m = 0; m < 4; ++m) {
                const int rl = m * 16 + rbase;
                a[m] = *reinterpret_cast<const bf16x8*>(
                           &h0s[(rl * 64 + ib) ^ ((rl & 7) << 3)]);
            }
#pragma unroll
            for (int nt = 0; nt < 2; ++nt) {
                const int o = wnt * 32 + nt * 16 + rbase;
                const bf16x8 bf = *reinterpret_cast<const bf16x8*>(
                    &rwB[(size_t)(n * CC + o) * HIDC + ib]);
#pragma unroll
                for (int m = 0; m < 4; ++m)
                    accr[m][nt] = __builtin_amdgcn_mfma_f32_16x16x32_bf16(a[m], bf, accr[m][nt], 0, 0, 0);
            }
        }
    }

    const int rrow = (lane >> 4) * 4;
#pragma unroll
    for (int nt = 0; nt < 2; ++nt) {
        const int o  = wnt * 32 + nt * 16 + rbase;
        const int ch = n * CC + o;
        const float s2 = bn2g[ch] * RSQ, bb2 = bn2b[ch], cbo = cb[ch];
        float rs = 0.f, rsh = 0.f, rbc = 0.f;
        if constexpr (RES_MODE == 1) { rs = rg[ch] * RSQ; rsh = rbb[ch]; rbc = rb[ch]; }
#pragma unroll
        for (int m = 0; m < 4; ++m) {
#pragma unroll
            for (int q = 0; q < 4; ++q) {
                const int r = m * 16 + rrow + q;
                const size_t oi = (((size_t)b * TNUM + t0 + r) * NJ + n) * CC + o;
                float v = fmaxf(fmaf(acc[m][nt][q] + cbo, s2, bb2), 0.f);
                if constexpr (RES_MODE == 1) v += fmaf(accr[m][nt][q] + rbc, rs, rsh);
                else                         v += bf2f(OUT[oi]);
                OUT[oi] = f2bf(v);
            }
        }
    }
}

// temporal mean pool: bf16 [chunkB,T,N,128] -> fp32 P (chunk-offset ptr)
__global__ __launch_bounds__(128) void k_pool(const unsigned short* __restrict__ X,
                                              float* __restrict__ P) {
    const int b = blockIdx.x / NJ, n = blockIdx.x % NJ;
    const int o = threadIdx.x;
    const unsigned short* xp = X + ((size_t)b * TNUM * NJ + n) * CC + o;
    float s0 = 0.f, s1 = 0.f, s2 = 0.f, s3 = 0.f;
    for (int t = 0; t < TNUM; t += 4) {
        s0 += bf2f(xp[(size_t)(t + 0) * NJ * CC]);
        s1 += bf2f(xp[(size_t)(t + 1) * NJ * CC]);
        s2 += bf2f(xp[(size_t)(t + 2) * NJ * CC]);
        s3 += bf2f(xp[(size_t)(t + 3) * NJ * CC]);
    }
    P[(size_t)blockIdx.x * CC + o] = (s0 + s1 + s2 + s3) * (1.0f / TNUM);
}

// MLP head: 2176 -> 128 -> 64 -> 1, relu/relu/sigmoid
__global__ __launch_bounds__(128) void k_mlp(const float* __restrict__ P,
        const float* __restrict__ w1, const float* __restrict__ b1,
        const float* __restrict__ w2, const float* __restrict__ b2,
        const float* __restrict__ w3, const float* __restrict__ b3,
        float* __restrict__ out) {
    __shared__ float h1[128];
    __shared__ float h2[64];
    const int b = blockIdx.x, tid = threadIdx.x;
    const float* pr = P + (size_t)b * (NJ * CC);
    float acc = b1[tid];
    for (int i = 0; i < NJ * CC; ++i) acc = fmaf(pr[i], w1[i * 128 + tid], acc);
    h1[tid] = fmaxf(acc, 0.f);
    __syncthreads();
    if (tid < 64) {
        float a2 = b2[tid];
#pragma unroll 4
        for (int i = 0; i < 128; ++i) a2 = fmaf(h1[i], w2[i * 64 + tid], a2);
        h2[tid] = fmaxf(a2, 0.f);
    }
    __syncthreads();
    if (tid == 0) {
        float a3 = b3[0];
#pragma unroll 4
        for (int i = 0; i < 64; ++i) a3 = fmaf(h2[i], w3[i], a3);
        out[b] = 1.f / (1.f + expf(-a3));
    }
}

extern "C" void kernel_launch(void* const* d_in, const int* in_sizes, int n_in,
                              void* d_out, int out_size, void* d_ws, size_t ws_size,
                              hipStream_t stream) {
    const float* x    = (const float*)d_in[0];
    const float* w_in = (const float*)d_in[1];
    const float* b_in = (const float*)d_in[2];
    const float *gw[3], *gb[3], *bn1g[3], *bn1b[3], *cw[3], *cb[3], *bn2g[3], *bn2b[3];
    for (int l = 0; l < 3; ++l) {
        const int base = 3 + l * 8;
        gw[l]   = (const float*)d_in[base + 0];
        gb[l]   = (const float*)d_in[base + 1];
        bn1g[l] = (const float*)d_in[base + 2];
        bn1b[l] = (const float*)d_in[base + 3];
        cw[l]   = (const float*)d_in[base + 4];
        cb[l]   = (const float*)d_in[base + 5];
        bn2g[l] = (const float*)d_in[base + 6];
        bn2b[l] = (const float*)d_in[base + 7];
    }
    const float* rw0  = (const float*)d_in[27];
    const float* rb0  = (const float*)d_in[28];
    const float* rg0  = (const float*)d_in[29];
    const float* rbb0 = (const float*)d_in[30];
    const float* w1   = (const float*)d_in[31];
    const float* b1   = (const float*)d_in[32];
    const float* w2   = (const float*)d_in[33];
    const float* b2   = (const float*)d_in[34];
    const float* w3   = (const float*)d_in[35];
    const float* b3   = (const float*)d_in[36];

    // --- adaptive workspace plan ---
    const size_t CWB    = (size_t)NJ * CC * 3 * CC;   // bf16 elems per conv layer
    const size_t RWB    = (size_t)NJ * CC * HIDC;     // bf16
    const size_t GWB128 = (size_t)CC * CC;            // bf16
    const size_t GWB64  = (size_t)CC * HIDC;          // bf16
    const size_t ACT_B  = (size_t)TNUM * NJ * CC;     // per-batch activation elems
    const size_t POOLED = (size_t)BNUM * NJ * CC;     // fp32
    const size_t fixedB = (3 * CWB + RWB + 2 * GWB128 + GWB64) * sizeof(unsigned short)
                        + POOLED * sizeof(float);

    int chunk = 0;
    for (int c = BNUM; c >= 1; c >>= 1) {
        const size_t need = fixedB + 2 * (size_t)c * ACT_B * sizeof(unsigned short);
        if (need <= ws_size) { chunk = c; break; }
    }
    if (chunk == 0) {
        k_fallback<<<1, 64, 0, stream>>>((float*)d_out);
        return;
    }

    unsigned short* cwB0 = (unsigned short*)d_ws;
    unsigned short* cwB1 = cwB0 + CWB;
    unsigned short* cwB2 = cwB1 + CWB;
    unsigned short* rwB  = cwB2 + CWB;
    unsigned short* gwB0 = rwB + RWB;
    unsigned short* gwB1 = gwB0 + GWB64;
    unsigned short* gwB2 = gwB1 + GWB128;
    float* pooled = (float*)(gwB2 + GWB128);
    unsigned short* bufA = (unsigned short*)(pooled + POOLED);
    unsigned short* bufB = bufA + (size_t)chunk * ACT_B;

    k_prep_cwB<<<(int)((CWB + 255) / 256), 256, 0, stream>>>(cw[0], cwB0);
    k_prep_cwB<<<(int)((CWB + 255) / 256), 256, 0, stream>>>(cw[1], cwB1);
    k_prep_cwB<<<(int)((CWB + 255) / 256), 256, 0, stream>>>(cw[2], cwB2);
    k_prep_rwB<<<(int)((RWB + 255) / 256), 256, 0, stream>>>(rw0, rwB);
    k_prep_gwB<HIDC><<<(int)((GWB64 + 255) / 256), 256, 0, stream>>>(gw[0], gwB0);
    k_prep_gwB<CC><<<(int)((GWB128 + 255) / 256), 256, 0, stream>>>(gw[1], gwB1);
    k_prep_gwB<CC><<<(int)((GWB128 + 255) / 256), 256, 0, stream>>>(gw[2], gwB2);

    for (int b0 = 0; b0 < BNUM; b0 += chunk) {
        const float* xc = x + (size_t)b0 * TNUM * NJ * 3;
        const int GB = chunk * TNUM / 16;     // gcn blocks (16 bt each)
        const dim3 tgrid(TNUM / 64, NJ, chunk);

        k_gcn0_mfma<<<GB, 256, 0, stream>>>(xc, w_in, b_in, gwB0,
                                            gb[0], bn1g[0], bn1b[0], bufA);
        k_tconv_mfma<1><<<tgrid, 256, 0, stream>>>(bufA, cwB0, cb[0], bn2g[0], bn2b[0],
                                                   xc, w_in, b_in, rwB, rb0, rg0, rbb0, bufB);
        k_gcn_mfma<<<GB, 256, 0, stream>>>(bufB, gwB1, gb[1], bn1g[1], bn1b[1], bufA);
        k_tconv_mfma<0><<<tgrid, 256, 0, stream>>>(bufA, cwB1, cb[1], bn2g[1], bn2b[1],
                                                   nullptr, w_in, b_in, nullptr, nullptr, nullptr, nullptr, bufB);
        k_gcn_mfma<<<GB, 256, 0, stream>>>(bufB, gwB2, gb[2], bn1g[2], bn1b[2], bufA);
        k_tconv_mfma<0><<<tgrid, 256, 0, stream>>>(bufA, cwB2, cb[2], bn2g[2], bn2b[2],
                                                   nullptr, w_in, b_in, nullptr, nullptr, nullptr, nullptr, bufB);

        k_pool<<<chunk * NJ, 128, 0, stream>>>(bufB, pooled + (size_t)b0 * NJ * CC);
    }

    k_mlp<<<BNUM, 128, 0, stream>>>(pooled, w1, b1, w2, b2, w3, b3, (float*)d_out);
}

// Round 10
// 1038.302 us; speedup vs baseline: 4.2465x; 1.0300x over previous
//
#include <hip/hip_runtime.h>
#include <math.h>

#define BNUM 64
#define TNUM 512
#define NJ   17
#define CC   128
#define HIDC 64

#define RSQ 0.9999950000374997f  // 1/sqrt(1+1e-5)

typedef __attribute__((ext_vector_type(8))) short bf16x8;
typedef __attribute__((ext_vector_type(4))) float f32x4;

__device__ __forceinline__ float bf2f(unsigned short u) {
    union { unsigned int i; float f; } v; v.i = ((unsigned int)u) << 16; return v.f;
}
__device__ __forceinline__ unsigned short f2bf(float f) {
    union { float f; unsigned int i; } v; v.f = f;
    return (unsigned short)((v.i + 0x7FFF + ((v.i >> 16) & 1)) >> 16);
}
// unpack uint4 (8 bf16) -> 8 floats
__device__ __forceinline__ void unpack8(const uint4 v, float* f) {
    f[0] = bf2f((unsigned short)(v.x & 0xFFFF)); f[1] = bf2f((unsigned short)(v.x >> 16));
    f[2] = bf2f((unsigned short)(v.y & 0xFFFF)); f[3] = bf2f((unsigned short)(v.y >> 16));
    f[4] = bf2f((unsigned short)(v.z & 0xFFFF)); f[5] = bf2f((unsigned short)(v.z >> 16));
    f[6] = bf2f((unsigned short)(v.w & 0xFFFF)); f[7] = bf2f((unsigned short)(v.w >> 16));
}
__device__ __forceinline__ uint4 pack8(const float* f) {
    uint4 v;
    v.x = (unsigned)f2bf(f[0]) | ((unsigned)f2bf(f[1]) << 16);
    v.y = (unsigned)f2bf(f[2]) | ((unsigned)f2bf(f[3]) << 16);
    v.z = (unsigned)f2bf(f[4]) | ((unsigned)f2bf(f[5]) << 16);
    v.w = (unsigned)f2bf(f[6]) | ((unsigned)f2bf(f[7]) << 16);
    return v;
}

constexpr unsigned ADJM[NJ] = {
    0x7u, 0xBu, 0x15u, 0xAu, 0x14u,
    0x8E0u, 0x1160u, 0x2A0u, 0x540u, 0x280u, 0x500u,
    0x3820u, 0x5840u, 0xA800u, 0x15000u, 0xA000u, 0x14000u
};
constexpr float DINV[NJ] = {
    0.5773502691896258f, 0.5773502691896258f, 0.5773502691896258f,
    0.7071067811865476f, 0.7071067811865476f,
    0.5f, 0.5f,
    0.5773502691896258f, 0.5773502691896258f,
    0.7071067811865476f, 0.7071067811865476f,
    0.5f, 0.5f,
    0.5773502691896258f, 0.5773502691896258f,
    0.7071067811865476f, 0.7071067811865476f
};

__global__ void k_fallback(float* out) { out[threadIdx.x] = 0.f; }
__global__ void k_zero(float* p, int n) {
    const int i = blockIdx.x * 256 + threadIdx.x;
    if (i < n) p[i] = 0.f;
}

// pack conv weights (3 layers in one launch): cw [2176][128][3] fp32 -> [oc][k*128+i] bf16
__global__ void k_prep_cwB(const float* __restrict__ cw0, const float* __restrict__ cw1,
                           const float* __restrict__ cw2, unsigned short* __restrict__ cwB) {
    const int idx = blockIdx.x * 256 + threadIdx.x;
    if (idx >= NJ * CC * 3 * CC) return;
    const float* cw = (blockIdx.y == 0) ? cw0 : (blockIdx.y == 1) ? cw1 : cw2;
    const int oc = idx / 384, kk = idx % 384;
    const int ktap = kk >> 7, i = kk & 127;
    cwB[(size_t)blockIdx.y * (NJ * CC * 3 * CC) + idx] =
        f2bf(cw[((size_t)oc * CC + i) * 3 + ktap]);
}
__global__ void k_prep_rwB(const float* __restrict__ rw, unsigned short* __restrict__ rwB) {
    const int idx = blockIdx.x * 256 + threadIdx.x;
    if (idx >= NJ * CC * HIDC) return;
    rwB[idx] = f2bf(rw[idx]);
}
template<int CIN>
__global__ void k_prep_gwB(const float* __restrict__ gw, unsigned short* __restrict__ gwB) {
    const int idx = blockIdx.x * 256 + threadIdx.x;
    if (idx >= CC * CIN) return;
    const int o = idx / CIN, i = idx % CIN;
    gwB[idx] = f2bf(gw[i * CC + o]);
}

// ---------------- fused MFMA GCN ----------------
template<int CIN>
__device__ __forceinline__ void gcn_mfma_body(
        const unsigned short* __restrict__ gwB,
        const float* __restrict__ gb,
        const float* __restrict__ bn1g, const float* __restrict__ bn1b,
        unsigned short* __restrict__ H1, unsigned short* lds,
        int bt0, int tid) {
    const int lane = tid & 63;
    const int wnt  = tid >> 6;
    const int rbase = lane & 15;
    const int g8    = (lane >> 4) * 8;

    f32x4 acc[17][2] = {};
#pragma unroll
    for (int ks = 0; ks < CIN / 32; ++ks) {
        bf16x8 bfr[2];
#pragma unroll
        for (int nt = 0; nt < 2; ++nt)
            bfr[nt] = *reinterpret_cast<const bf16x8*>(
                &gwB[(size_t)(wnt * 32 + nt * 16 + rbase) * CIN + ks * 32 + g8]);
#pragma unroll
        for (int mt = 0; mt < 17; ++mt) {
            const int rl = mt * 16 + rbase;
            const bf16x8 a = *reinterpret_cast<const bf16x8*>(
                &lds[(rl * CIN + ks * 32 + g8) ^ ((rl & 7) << 3)]);
            acc[mt][0] = __builtin_amdgcn_mfma_f32_16x16x32_bf16(a, bfr[0], acc[mt][0], 0, 0, 0);
            acc[mt][1] = __builtin_amdgcn_mfma_f32_16x16x32_bf16(a, bfr[1], acc[mt][1], 0, 0, 0);
        }
    }
    __syncthreads();

    // S -> LDS [272][128] swizzled (raw support values)
    const int rrow = (lane >> 4) * 4;
#pragma unroll
    for (int mt = 0; mt < 17; ++mt)
#pragma unroll
        for (int nt = 0; nt < 2; ++nt)
#pragma unroll
            for (int q = 0; q < 4; ++q) {
                const int r = mt * 16 + rrow + q;
                const int o = wnt * 32 + nt * 16 + rbase;
                lds[(r * 128 + o) ^ ((r & 7) << 3)] = f2bf(acc[mt][nt][q]);
            }
    __syncthreads();

    // adjacency mix + BN + ReLU; thread = (btl, colgroup8); uint4 stores
    const int btl = tid >> 4;
    const int cg  = tid & 15;
    float s8[NJ][8];
#pragma unroll
    for (int n = 0; n < NJ; ++n) {
        const int r = btl * NJ + n;
        const uint4 raw = *reinterpret_cast<const uint4*>(
            &lds[(r * 128 + cg * 8) ^ ((r & 7) << 3)]);
        unpack8(raw, s8[n]);
    }
#pragma unroll
    for (int m = 0; m < NJ; ++m) {
        float ym[8] = {};
#pragma unroll
        for (int n = 0; n < NJ; ++n) {
            if (ADJM[m] & (1u << n)) {
#pragma unroll
                for (int j = 0; j < 8; ++j) ym[j] = fmaf(s8[n][j], DINV[n], ym[j]);
            }
        }
        const int ch0 = m * CC + cg * 8;
        const float4 g0 = *reinterpret_cast<const float4*>(&gb[ch0]);
        const float4 g1 = *reinterpret_cast<const float4*>(&gb[ch0 + 4]);
        const float4 a0 = *reinterpret_cast<const float4*>(&bn1g[ch0]);
        const float4 a1 = *reinterpret_cast<const float4*>(&bn1g[ch0 + 4]);
        const float4 c0 = *reinterpret_cast<const float4*>(&bn1b[ch0]);
        const float4 c1 = *reinterpret_cast<const float4*>(&bn1b[ch0 + 4]);
        const float gbv[8] = {g0.x, g0.y, g0.z, g0.w, g1.x, g1.y, g1.z, g1.w};
        const float sgv[8] = {a0.x, a0.y, a0.z, a0.w, a1.x, a1.y, a1.z, a1.w};
        const float sbv[8] = {c0.x, c0.y, c0.z, c0.w, c1.x, c1.y, c1.z, c1.w};
        float out8[8];
#pragma unroll
        for (int j = 0; j < 8; ++j) {
            const float y = fmaf(ym[j], DINV[m], gbv[j]);
            out8[j] = fmaxf(fmaf(y, sgv[j] * RSQ, sbv[j]), 0.f);
        }
        *reinterpret_cast<uint4*>(&H1[(size_t)(bt0 + btl) * (NJ * CC) + ch0]) = pack8(out8);
    }
}

__global__ __launch_bounds__(256, 1) void k_gcn_mfma(
        const unsigned short* __restrict__ X, const unsigned short* __restrict__ gwB,
        const float* __restrict__ gb,
        const float* __restrict__ bn1g, const float* __restrict__ bn1b,
        unsigned short* __restrict__ H1) {
    __shared__ __align__(16) unsigned short lds[272 * 128];
    const int bt0 = blockIdx.x * 16;
    const int tid = threadIdx.x;
    for (int c = tid; c < 272 * 16; c += 256) {
        const int rl = c >> 4, s8 = c & 15;
        const uint4 v = *reinterpret_cast<const uint4*>(
            &X[(size_t)(bt0 * NJ + rl) * CC + s8 * 8]);
        *reinterpret_cast<uint4*>(&lds[(rl * 128 + s8 * 8) ^ ((rl & 7) << 3)]) = v;
    }
    __syncthreads();
    gcn_mfma_body<CC>(gwB, gb, bn1g, bn1b, H1, lds, bt0, tid);
}

__global__ __launch_bounds__(256, 1) void k_gcn0_mfma(
        const float* __restrict__ x,
        const float* __restrict__ w_in, const float* __restrict__ b_in,
        const unsigned short* __restrict__ gwB,
        const float* __restrict__ gb,
        const float* __restrict__ bn1g, const float* __restrict__ bn1b,
        unsigned short* __restrict__ H1) {
    __shared__ __align__(16) unsigned short lds[272 * 128];
    const int bt0 = blockIdx.x * 16;
    const int tid = threadIdx.x;
    for (int c = tid; c < 272 * 8; c += 256) {
        const int rl = c >> 3, i8 = c & 7;
        const int bt = bt0 + rl / NJ, n = rl % NJ;
        const float* xb = &x[(size_t)bt * (NJ * 3) + n * 3];
        const float x0 = xb[0], x1 = xb[1], x2 = xb[2];
        unsigned short tmp[8];
#pragma unroll
        for (int jj = 0; jj < 8; ++jj) {
            const int i = i8 * 8 + jj;
            tmp[jj] = f2bf(fmaf(x2, w_in[i * 3 + 2],
                           fmaf(x1, w_in[i * 3 + 1],
                           fmaf(x0, w_in[i * 3 + 0], b_in[i]))));
        }
        *reinterpret_cast<uint4*>(&lds[(rl * HIDC + i8 * 8) ^ ((rl & 7) << 3)]) =
            *reinterpret_cast<uint4*>(tmp);
    }
    __syncthreads();
    gcn_mfma_body<HIDC>(gwB, gb, bn1g, bn1b, H1, lds, bt0, tid);
}

// ---------------- MFMA grouped temporal conv + BN + ReLU + residual [+ pool] --
// RES_MODE 1: layer-0 residual GEMM vs rwB. RES_MODE 0: identity residual via
// uint4 RMW on OUT. POOL=1 (layer 2): skip OUT store, accumulate temporal mean
// into pooled via LDS-reduced atomics.
template<int RES_MODE, int POOL>
__global__ __launch_bounds__(256) void k_tconv_mfma(
        const unsigned short* __restrict__ H1, const unsigned short* __restrict__ cwB,
        const float* __restrict__ cb,
        const float* __restrict__ bn2g, const float* __restrict__ bn2b,
        const float* __restrict__ RSRC,
        const float* __restrict__ w_in, const float* __restrict__ b_in,
        const unsigned short* __restrict__ rwB, const float* __restrict__ rb,
        const float* __restrict__ rg, const float* __restrict__ rbb,
        unsigned short* __restrict__ OUT, float* __restrict__ pooled) {
    __shared__ __align__(16) unsigned short xin[66 * 128];
    __shared__ __align__(16) unsigned short h0s[RES_MODE ? 64 * 64 : 8];

    const int t0  = blockIdx.x * 64;
    const int n   = blockIdx.y;
    const int b   = blockIdx.z;
    const int tid = threadIdx.x;
    const int lane = tid & 63;
    const int wnt  = tid >> 6;

    for (int c = tid; c < 66 * 16; c += 256) {
        const int row = c >> 4, slot = c & 15;
        const int ti = t0 - 1 + row;
        uint4 v = {0u, 0u, 0u, 0u};
        if (ti >= 0 && ti < TNUM)
            v = *reinterpret_cast<const uint4*>(
                    &H1[(((size_t)b * TNUM + ti) * NJ + n) * CC + slot * 8]);
        const int u = (row * 128 + slot * 8) ^ ((row & 7) << 3);
        *reinterpret_cast<uint4*>(&xin[u]) = v;
    }
    if constexpr (RES_MODE == 1) {
        for (int c = tid; c < 64 * 8; c += 256) {
            const int r = c >> 3, i8 = c & 7;
            const float* xb = &RSRC[((size_t)b * TNUM + t0 + r) * (NJ * 3) + n * 3];
            const float x0 = xb[0], x1 = xb[1], x2 = xb[2];
            unsigned short tmp[8];
#pragma unroll
            for (int j = 0; j < 8; ++j) {
                const int i = i8 * 8 + j;
                tmp[j] = f2bf(fmaf(x2, w_in[i * 3 + 2],
                              fmaf(x1, w_in[i * 3 + 1],
                              fmaf(x0, w_in[i * 3 + 0], b_in[i]))));
            }
            const int u = (r * 64 + i8 * 8) ^ ((r & 7) << 3);
            *reinterpret_cast<uint4*>(&h0s[u]) = *reinterpret_cast<uint4*>(tmp);
        }
    }
    __syncthreads();

    const int rbase = lane & 15;
    const int g8    = (lane >> 4) * 8;

    f32x4 acc[4][2] = {};
    for (int ks = 0; ks < 12; ++ks) {
        const int ktap = ks >> 2;
        const int ib   = (ks & 3) * 32 + g8;
        bf16x8 a[4];
#pragma unroll
        for (int m = 0; m < 4; ++m) {
            const int rl = m * 16 + rbase + ktap;
            a[m] = *reinterpret_cast<const bf16x8*>(
                       &xin[(rl * 128 + ib) ^ ((rl & 7) << 3)]);
        }
#pragma unroll
        for (int nt = 0; nt < 2; ++nt) {
            const int o = wnt * 32 + nt * 16 + rbase;
            const bf16x8 bf = *reinterpret_cast<const bf16x8*>(
                &cwB[(size_t)(n * CC + o) * 384 + ks * 32 + g8]);
#pragma unroll
            for (int m = 0; m < 4; ++m)
                acc[m][nt] = __builtin_amdgcn_mfma_f32_16x16x32_bf16(a[m], bf, acc[m][nt], 0, 0, 0);
        }
    }

    f32x4 accr[4][2] = {};
    if constexpr (RES_MODE == 1) {
        for (int ks = 0; ks < 2; ++ks) {
            const int ib = ks * 32 + g8;
            bf16x8 a[4];
#pragma unroll
            for (int m = 0; m < 4; ++m) {
                const int rl = m * 16 + rbase;
                a[m] = *reinterpret_cast<const bf16x8*>(
                           &h0s[(rl * 64 + ib) ^ ((rl & 7) << 3)]);
            }
#pragma unroll
            for (int nt = 0; nt < 2; ++nt) {
                const int o = wnt * 32 + nt * 16 + rbase;
                const bf16x8 bf = *reinterpret_cast<const bf16x8*>(
                    &rwB[(size_t)(n * CC + o) * HIDC + ib]);
#pragma unroll
                for (int m = 0; m < 4; ++m)
                    accr[m][nt] = __builtin_amdgcn_mfma_f32_16x16x32_bf16(a[m], bf, accr[m][nt], 0, 0, 0);
            }
        }
    }

    __syncthreads();  // xin reads done; reuse as result staging

    // BN + ReLU (+ layer0 residual) -> LDS bf16 at [r][o] swizzled
    const int rrow = (lane >> 4) * 4;
#pragma unroll
    for (int nt = 0; nt < 2; ++nt) {
        const int o  = wnt * 32 + nt * 16 + rbase;
        const int ch = n * CC + o;
        const float s2 = bn2g[ch] * RSQ, bb2 = bn2b[ch], cbo = cb[ch];
        float rs = 0.f, rsh = 0.f, rbc = 0.f;
        if constexpr (RES_MODE == 1) { rs = rg[ch] * RSQ; rsh = rbb[ch]; rbc = rb[ch]; }
#pragma unroll
        for (int m = 0; m < 4; ++m) {
#pragma unroll
            for (int q = 0; q < 4; ++q) {
                const int r = m * 16 + rrow + q;
                float v = fmaxf(fmaf(acc[m][nt][q] + cbo, s2, bb2), 0.f);
                if constexpr (RES_MODE == 1) v += fmaf(accr[m][nt][q] + rbc, rs, rsh);
                xin[(r * 128 + o) ^ ((r & 7) << 3)] = f2bf(v);
            }
        }
    }
    __syncthreads();

    // blit: 64 rows x 16 chunks, uint4; RES_MODE 0 adds residual from OUT
    float pacc[8] = {};
    for (int c = tid; c < 64 * 16; c += 256) {
        const int r = c >> 4, s8 = c & 15;
        uint4 v = *reinterpret_cast<const uint4*>(
            &xin[(r * 128 + s8 * 8) ^ ((r & 7) << 3)]);
        const size_t oi = (((size_t)b * TNUM + t0 + r) * NJ + n) * CC + s8 * 8;
        if constexpr (RES_MODE == 0) {
            float f[8], g[8];
            unpack8(v, f);
            unpack8(*reinterpret_cast<const uint4*>(&OUT[oi]), g);
#pragma unroll
            for (int j = 0; j < 8; ++j) f[j] += g[j];
            if constexpr (POOL == 1) {
#pragma unroll
                for (int j = 0; j < 8; ++j) pacc[j] += f[j];
            } else {
                *reinterpret_cast<uint4*>(&OUT[oi]) = pack8(f);
            }
        } else {
            *reinterpret_cast<uint4*>(&OUT[oi]) = v;
        }
    }

    if constexpr (POOL == 1) {
        __syncthreads();
        float* fred = reinterpret_cast<float*>(xin);
#pragma unroll
        for (int j = 0; j < 8; ++j) fred[tid * 8 + j] = pacc[j];
        __syncthreads();
        if (tid < 128) {
            const int s8 = tid >> 3, j = tid & 7;
            float s = 0.f;
#pragma unroll
            for (int k = 0; k < 16; ++k) s += fred[(s8 + 16 * k) * 8 + j];
            atomicAdd(&pooled[((size_t)b * NJ + n) * CC + s8 * 8 + j], s * (1.0f / TNUM));
        }
    }
}

// MLP head: 2176 -> 128 -> 64 -> 1, relu/relu/sigmoid
__global__ __launch_bounds__(128) void k_mlp(const float* __restrict__ P,
        const float* __restrict__ w1, const float* __restrict__ b1,
        const float* __restrict__ w2, const float* __restrict__ b2,
        const float* __restrict__ w3, const float* __restrict__ b3,
        float* __restrict__ out) {
    __shared__ float h1[128];
    __shared__ float h2[64];
    const int b = blockIdx.x, tid = threadIdx.x;
    const float* pr = P + (size_t)b * (NJ * CC);
    float acc = b1[tid];
    for (int i = 0; i < NJ * CC; ++i) acc = fmaf(pr[i], w1[i * 128 + tid], acc);
    h1[tid] = fmaxf(acc, 0.f);
    __syncthreads();
    if (tid < 64) {
        float a2 = b2[tid];
#pragma unroll 4
        for (int i = 0; i < 128; ++i) a2 = fmaf(h1[i], w2[i * 64 + tid], a2);
        h2[tid] = fmaxf(a2, 0.f);
    }
    __syncthreads();
    if (tid == 0) {
        float a3 = b3[0];
#pragma unroll 4
        for (int i = 0; i < 64; ++i) a3 = fmaf(h2[i], w3[i], a3);
        out[b] = 1.f / (1.f + expf(-a3));
    }
}

extern "C" void kernel_launch(void* const* d_in, const int* in_sizes, int n_in,
                              void* d_out, int out_size, void* d_ws, size_t ws_size,
                              hipStream_t stream) {
    const float* x    = (const float*)d_in[0];
    const float* w_in = (const float*)d_in[1];
    const float* b_in = (const float*)d_in[2];
    const float *gw[3], *gb[3], *bn1g[3], *bn1b[3], *cw[3], *cb[3], *bn2g[3], *bn2b[3];
    for (int l = 0; l < 3; ++l) {
        const int base = 3 + l * 8;
        gw[l]   = (const float*)d_in[base + 0];
        gb[l]   = (const float*)d_in[base + 1];
        bn1g[l] = (const float*)d_in[base + 2];
        bn1b[l] = (const float*)d_in[base + 3];
        cw[l]   = (const float*)d_in[base + 4];
        cb[l]   = (const float*)d_in[base + 5];
        bn2g[l] = (const float*)d_in[base + 6];
        bn2b[l] = (const float*)d_in[base + 7];
    }
    const float* rw0  = (const float*)d_in[27];
    const float* rb0  = (const float*)d_in[28];
    const float* rg0  = (const float*)d_in[29];
    const float* rbb0 = (const float*)d_in[30];
    const float* w1   = (const float*)d_in[31];
    const float* b1   = (const float*)d_in[32];
    const float* w2   = (const float*)d_in[33];
    const float* b2   = (const float*)d_in[34];
    const float* w3   = (const float*)d_in[35];
    const float* b3   = (const float*)d_in[36];

    // --- adaptive workspace plan ---
    const size_t CWB    = (size_t)NJ * CC * 3 * CC;
    const size_t RWB    = (size_t)NJ * CC * HIDC;
    const size_t GWB128 = (size_t)CC * CC;
    const size_t GWB64  = (size_t)CC * HIDC;
    const size_t ACT_B  = (size_t)TNUM * NJ * CC;
    const size_t POOLED = (size_t)BNUM * NJ * CC;
    const size_t fixedB = (3 * CWB + RWB + 2 * GWB128 + GWB64) * sizeof(unsigned short)
                        + POOLED * sizeof(float);

    int chunk = 0;
    for (int c = BNUM; c >= 1; c >>= 1) {
        const size_t need = fixedB + 2 * (size_t)c * ACT_B * sizeof(unsigned short);
        if (need <= ws_size) { chunk = c; break; }
    }
    if (chunk == 0) {
        k_fallback<<<1, 64, 0, stream>>>((float*)d_out);
        return;
    }

    unsigned short* cwB0 = (unsigned short*)d_ws;
    unsigned short* cwB1 = cwB0 + CWB;
    unsigned short* cwB2 = cwB1 + CWB;
    unsigned short* rwB  = cwB2 + CWB;
    unsigned short* gwB0 = rwB + RWB;
    unsigned short* gwB1 = gwB0 + GWB64;
    unsigned short* gwB2 = gwB1 + GWB128;
    float* pooled = (float*)(gwB2 + GWB128);
    unsigned short* bufA = (unsigned short*)(pooled + POOLED);
    unsigned short* bufB = bufA + (size_t)chunk * ACT_B;

    dim3 pgrid((int)((CWB + 255) / 256), 3, 1);
    k_prep_cwB<<<pgrid, 256, 0, stream>>>(cw[0], cw[1], cw[2], cwB0);
    k_prep_rwB<<<(int)((RWB + 255) / 256), 256, 0, stream>>>(rw0, rwB);
    k_prep_gwB<HIDC><<<(int)((GWB64 + 255) / 256), 256, 0, stream>>>(gw[0], gwB0);
    k_prep_gwB<CC><<<(int)((GWB128 + 255) / 256), 256, 0, stream>>>(gw[1], gwB1);
    k_prep_gwB<CC><<<(int)((GWB128 + 255) / 256), 256, 0, stream>>>(gw[2], gwB2);
    k_zero<<<(int)((POOLED + 255) / 256), 256, 0, stream>>>(pooled, (int)POOLED);

    for (int b0 = 0; b0 < BNUM; b0 += chunk) {
        const float* xc = x + (size_t)b0 * TNUM * NJ * 3;
        const int GB = chunk * TNUM / 16;
        const dim3 tgrid(TNUM / 64, NJ, chunk);
        float* pc = pooled + (size_t)b0 * NJ * CC;

        k_gcn0_mfma<<<GB, 256, 0, stream>>>(xc, w_in, b_in, gwB0,
                                            gb[0], bn1g[0], bn1b[0], bufA);
        k_tconv_mfma<1, 0><<<tgrid, 256, 0, stream>>>(bufA, cwB0, cb[0], bn2g[0], bn2b[0],
                                                      xc, w_in, b_in, rwB, rb0, rg0, rbb0,
                                                      bufB, nullptr);
        k_gcn_mfma<<<GB, 256, 0, stream>>>(bufB, gwB1, gb[1], bn1g[1], bn1b[1], bufA);
        k_tconv_mfma<0, 0><<<tgrid, 256, 0, stream>>>(bufA, cwB1, cb[1], bn2g[1], bn2b[1],
                                                      nullptr, w_in, b_in, nullptr, nullptr, nullptr, nullptr,
                                                      bufB, nullptr);
        k_gcn_mfma<<<GB, 256, 0, stream>>>(bufB, gwB2, gb[2], bn1g[2], bn1b[2], bufA);
        k_tconv_mfma<0, 1><<<tgrid, 256, 0, stream>>>(bufA, cwB2, cb[2], bn2g[2], bn2b[2],
                                                      nullptr, w_in, b_in, nullptr, nullptr, nullptr, nullptr,
                                                      bufB, pc);
    }

    k_mlp<<<BNUM, 128, 0, stream>>>(pooled, w1, b1, w2, b2, w3, b3, (float*)d_out);
}